// Round 3
// baseline (853.871 us; speedup 1.0000x reference)
//
#include <hip/hip_runtime.h>

// ---------------------------------------------------------------------------
// TemporalAttention: x@Wq/Wk/Wv -> RoPE -> causal SDPA -> @Wo
// B=2 T=2048 DM=2048 H=16 HD=128.  Outputs: out f32[2,2048,2048],
// k_roped f32[2,16,2048,128], v f32[2,16,2048,128] concatenated in d_out.
// ---------------------------------------------------------------------------

typedef __bf16 bf16;
typedef __attribute__((ext_vector_type(8))) __bf16 bf16x8;
typedef __attribute__((ext_vector_type(4))) __bf16 bf16x4;
typedef __attribute__((ext_vector_type(4))) float f32x4;

__device__ __forceinline__ void gload_lds16(const void* g, void* l) {
  __builtin_amdgcn_global_load_lds((const __attribute__((address_space(1))) void*)g,
                                   (__attribute__((address_space(3))) void*)l, 16, 0, 0);
}

// ---- x f32 -> bf16 (vector4) ----------------------------------------------
__global__ __launch_bounds__(256) void k_convert(const float* __restrict__ in,
                                                 bf16* __restrict__ out, int n4) {
  int i = blockIdx.x * 256 + threadIdx.x;
  if (i >= n4) return;
  float4 v = ((const float4*)in)[i];
  bf16x4 o;
  o.x = (bf16)v.x; o.y = (bf16)v.y; o.z = (bf16)v.z; o.w = (bf16)v.w;
  ((bf16x4*)out)[i] = o;
}

// ---- W [K][N] f32 -> WT [N][K] bf16, 4 matrices via z ----------------------
__global__ __launch_bounds__(256) void k_transpose_w(
    const float* __restrict__ W0, const float* __restrict__ W1,
    const float* __restrict__ W2, const float* __restrict__ W3,
    bf16* __restrict__ T0, bf16* __restrict__ T1,
    bf16* __restrict__ T2, bf16* __restrict__ T3) {
  __shared__ float tile[32][33];
  const float* W; bf16* To;
  switch (blockIdx.z) {
    case 0: W = W0; To = T0; break;
    case 1: W = W1; To = T1; break;
    case 2: W = W2; To = T2; break;
    default: W = W3; To = T3; break;
  }
  int n0 = blockIdx.x * 32, k0 = blockIdx.y * 32;
  int tx = threadIdx.x, ty = threadIdx.y;  // (32,8)
#pragma unroll
  for (int j = 0; j < 4; ++j)
    tile[ty + 8 * j][tx] = W[(size_t)(k0 + ty + 8 * j) * 2048 + n0 + tx];
  __syncthreads();
#pragma unroll
  for (int j = 0; j < 4; ++j)
    To[(size_t)(n0 + ty + 8 * j) * 2048 + k0 + tx] = (bf16)tile[tx][ty + 8 * j];
}

// ---- GEMM C[4096x2048] = A[4096x2048] * Bt^T  (Bt is [N][K] row-major) -----
// 128x128 tile, BK=64, 4 waves each 64x64, mfma_f32_16x16x32_bf16.
// MODE 0: write bf16 into [B,H,T,HD] (z selects Wq/Wk/Wv). MODE 1: f32 row-major.
template <int MODE>
__global__ __launch_bounds__(256) void k_gemm(
    const bf16* __restrict__ A, const bf16* __restrict__ B0,
    const bf16* __restrict__ B1, const bf16* __restrict__ B2,
    bf16* __restrict__ o0, bf16* __restrict__ o1, bf16* __restrict__ o2,
    float* __restrict__ outf) {
  __shared__ __align__(16) bf16 Al[128 * 64];
  __shared__ __align__(16) bf16 Bl[128 * 64];
  const bf16* Bt; bf16* outb = nullptr;
  if (MODE == 0) {
    switch (blockIdx.z) {
      case 0: Bt = B0; outb = o0; break;
      case 1: Bt = B1; outb = o1; break;
      default: Bt = B2; outb = o2; break;
    }
  } else {
    Bt = B0;
  }
  int t = threadIdx.x;
  int wv = t >> 6, lane = t & 63, lr = lane & 15, lg = lane >> 4;
  int wr = wv >> 1, wc = wv & 1;
  int row0 = blockIdx.x * 128, col0 = blockIdx.y * 128;
  f32x4 acc[4][4] = {};
  for (int kt = 0; kt < 32; ++kt) {
    int k0 = kt * 64;
#pragma unroll
    for (int it = 0; it < 4; ++it) {
      int ci = it * 256 + t;            // chunk 0..1023, 16B each
      int r = ci >> 3, c8 = (ci & 7) * 8;
      int base = __builtin_amdgcn_readfirstlane(it * 256 + (t & ~63));
      gload_lds16(A + (size_t)(row0 + r) * 2048 + k0 + c8, Al + (size_t)base * 8);
      gload_lds16(Bt + (size_t)(col0 + r) * 2048 + k0 + c8, Bl + (size_t)base * 8);
    }
    __syncthreads();
#pragma unroll
    for (int kk = 0; kk < 2; ++kk) {
      bf16x8 af[4], bfr[4];
#pragma unroll
      for (int mf = 0; mf < 4; ++mf)
        af[mf] = *(const bf16x8*)(Al + (wr * 64 + mf * 16 + lr) * 64 + kk * 32 + lg * 8);
#pragma unroll
      for (int nf = 0; nf < 4; ++nf)
        bfr[nf] = *(const bf16x8*)(Bl + (wc * 64 + nf * 16 + lr) * 64 + kk * 32 + lg * 8);
#pragma unroll
      for (int mf = 0; mf < 4; ++mf)
#pragma unroll
        for (int nf = 0; nf < 4; ++nf)
          acc[mf][nf] = __builtin_amdgcn_mfma_f32_16x16x32_bf16(af[mf], bfr[nf], acc[mf][nf], 0, 0, 0);
    }
    __syncthreads();
  }
#pragma unroll
  for (int mf = 0; mf < 4; ++mf)
#pragma unroll
    for (int nf = 0; nf < 4; ++nf)
#pragma unroll
      for (int r = 0; r < 4; ++r) {
        int row = row0 + wr * 64 + mf * 16 + lg * 4 + r;  // C row (m), verified layout
        int col = col0 + wc * 64 + nf * 16 + lr;          // C col (n)
        float v = acc[mf][nf][r];
        if (MODE == 0) {
          int b = row >> 11, tt = row & 2047, h = col >> 7, d = col & 127;
          outb[(size_t)((b * 16 + h) * 2048 + tt) * 128 + d] = (bf16)v;
        } else {
          outf[(size_t)row * 2048 + col] = v;
        }
      }
}

// ---- RoPE in-place on q,k (bf16); emit k_roped f32 + v f32 outputs ---------
__global__ __launch_bounds__(256) void k_rope(
    bf16* __restrict__ q, bf16* __restrict__ k, const bf16* __restrict__ v,
    const float* __restrict__ cosb, const float* __restrict__ sinb,
    float* __restrict__ kout, float* __restrict__ vout) {
  int tid = blockIdx.x * 256 + threadIdx.x;
  int d = tid & 63;
  int row = tid >> 6;              // (b*16+h)*2048 + t, 0..65535
  int t = row & 2047;
  size_t base = (size_t)row * 128;
  float c1 = cosb[t * 128 + d], c2 = cosb[t * 128 + 64 + d];
  float s1 = sinb[t * 128 + d], s2 = sinb[t * 128 + 64 + d];
  float qlo = (float)q[base + d], qhi = (float)q[base + 64 + d];
  float klo = (float)k[base + d], khi = (float)k[base + 64 + d];
  float ql = qlo * c1 - qhi * s1, qh = qhi * c2 + qlo * s2;
  float kl = klo * c1 - khi * s1, kh = khi * c2 + klo * s2;
  q[base + d] = (bf16)ql; q[base + 64 + d] = (bf16)qh;
  k[base + d] = (bf16)kl; k[base + 64 + d] = (bf16)kh;
  kout[base + d] = kl; kout[base + 64 + d] = kh;
  vout[base + d] = (float)v[base + d];
  vout[base + 64 + d] = (float)v[base + 64 + d];
}

// ---- V [bh][T][HD] -> VT [bh][HD][T] bf16 ----------------------------------
__global__ __launch_bounds__(256) void k_vt(const bf16* __restrict__ v,
                                            bf16* __restrict__ vt) {
  __shared__ bf16 tile[32][33];
  int bh = blockIdx.z;
  int t0 = blockIdx.x * 32, d0 = blockIdx.y * 32;
  int tx = threadIdx.x, ty = threadIdx.y;  // (32,8)
  const bf16* vb = v + (size_t)bh * 2048 * 128;
  bf16* vtb = vt + (size_t)bh * 128 * 2048;
#pragma unroll
  for (int j = 0; j < 4; ++j)
    tile[ty + 8 * j][tx] = vb[(size_t)(t0 + ty + 8 * j) * 128 + d0 + tx];
  __syncthreads();
#pragma unroll
  for (int j = 0; j < 4; ++j)
    vtb[(size_t)(d0 + ty + 8 * j) * 2048 + t0 + tx] = tile[tx][ty + 8 * j];
}

// ---- causal flash attention, barrier-free, QBLK=64 -------------------------
// grid (32 qblocks reversed, 32 bh); 4 waves x 16 q-rows each.
// KV tile = 64. Every wave is active in every tile (causality via -1e30 mask
// only) -> no divergence.  K and V^T fragments load DIRECTLY from global
// (L2-resident; per-head K,V = 512KB each).  P round-trips through per-wave
// LDS with XOR swizzle (col ^= (row&7)*8): b128 reads land 8 distinct 16B
// slots / 2-way bank alias (free).  No __syncthreads in the loop: DS ops are
// wave-ordered; explicit lgkmcnt(0) + sched_barrier(0) fences P write->read.
// __launch_bounds__(256,4): VGPR<=128 -> 4 blocks/CU resident (16 waves/CU).
__global__ __launch_bounds__(256, 4) void k_attn(
    const bf16* __restrict__ Q, const bf16* __restrict__ Kr,
    const bf16* __restrict__ Vt, bf16* __restrict__ O) {
  __shared__ __align__(16) bf16 Pl[4][16][64];   // [wave][q16][kv64] 8KB
  int t = threadIdx.x, wv = t >> 6, lane = t & 63, lr = lane & 15, lg = lane >> 4;
  int qb = (int)gridDim.x - 1 - (int)blockIdx.x;    // heavy blocks first
  int bh = blockIdx.y;
  const bf16* Qb = Q + (size_t)bh * 2048 * 128;
  const bf16* Kb = Kr + (size_t)bh * 2048 * 128;
  const bf16* Vb = Vt + (size_t)bh * 128 * 2048;
  int wq0 = qb * 64 + wv * 16;
  bf16x8 qf[4];
#pragma unroll
  for (int df = 0; df < 4; ++df)
    qf[df] = *(const bf16x8*)(Qb + (size_t)(wq0 + lr) * 128 + df * 32 + lg * 8);
  f32x4 od[8] = {};
  float m_run[4], l_run[4];
#pragma unroll
  for (int r = 0; r < 4; ++r) { m_run[r] = -1e30f; l_run[r] = 0.f; }
  const float scale = 0.08838834764831845f;
  int nkt = qb + 1;
  for (int kt = 0; kt < nkt; ++kt) {
    int kv0 = kt * 64;
    // ---- QK^T: S[c] (16q x 16kv each), K frags direct from global ----
    f32x4 s[4] = {};
#pragma unroll
    for (int c = 0; c < 4; ++c) {
      bf16x8 kf[4];
#pragma unroll
      for (int df = 0; df < 4; ++df)
        kf[df] = *(const bf16x8*)(Kb + (size_t)(kv0 + c * 16 + lr) * 128 + df * 32 + lg * 8);
#pragma unroll
      for (int df = 0; df < 4; ++df)
        s[c] = __builtin_amdgcn_mfma_f32_16x16x32_bf16(qf[df], kf[df], s[c], 0, 0, 0);
    }
    // ---- online softmax ----
    float corr[4];
#pragma unroll
    for (int r = 0; r < 4; ++r) {
      int qrow = wq0 + lg * 4 + r;
      float sv[4];
#pragma unroll
      for (int c = 0; c < 4; ++c) {
        sv[c] = s[c][r] * scale;
        if (kv0 + c * 16 + lr > qrow) sv[c] = -1e30f;
      }
      float mx = fmaxf(fmaxf(sv[0], sv[1]), fmaxf(sv[2], sv[3]));
      mx = fmaxf(mx, __shfl_xor(mx, 1));
      mx = fmaxf(mx, __shfl_xor(mx, 2));
      mx = fmaxf(mx, __shfl_xor(mx, 4));
      mx = fmaxf(mx, __shfl_xor(mx, 8));
      float mnew = fmaxf(m_run[r], mx);
      float cr = __expf(m_run[r] - mnew);
      float pv0 = __expf(sv[0] - mnew), pv1 = __expf(sv[1] - mnew);
      float pv2 = __expf(sv[2] - mnew), pv3 = __expf(sv[3] - mnew);
      float rs = pv0 + pv1 + pv2 + pv3;
      rs += __shfl_xor(rs, 1); rs += __shfl_xor(rs, 2);
      rs += __shfl_xor(rs, 4); rs += __shfl_xor(rs, 8);
      l_run[r] = l_run[r] * cr + rs;
      m_run[r] = mnew;
      corr[r] = cr;
      int row = lg * 4 + r, sw = (row & 7) * 8;
      Pl[wv][row][(0 * 16 + lr) ^ sw] = (bf16)pv0;
      Pl[wv][row][(1 * 16 + lr) ^ sw] = (bf16)pv1;
      Pl[wv][row][(2 * 16 + lr) ^ sw] = (bf16)pv2;
      Pl[wv][row][(3 * 16 + lr) ^ sw] = (bf16)pv3;
    }
#pragma unroll
    for (int db = 0; db < 8; ++db)
#pragma unroll
      for (int r = 0; r < 4; ++r) od[db][r] *= corr[r];
    // fence P write -> P read (same wave, cross-lane): drain lgkm, pin order
    __builtin_amdgcn_sched_barrier(0);
    __builtin_amdgcn_s_waitcnt(0xc07f);   // lgkmcnt(0), vmcnt/exp unconstrained
    __builtin_amdgcn_sched_barrier(0);
    // ---- PV: A = P (from LDS, swizzled b128), B = V^T direct from global --
    bf16x8 pa[2];
#pragma unroll
    for (int kk = 0; kk < 2; ++kk)
      pa[kk] = *(const bf16x8*)(&Pl[wv][lr][(kk * 32 + lg * 8) ^ ((lr & 7) * 8)]);
#pragma unroll
    for (int kk = 0; kk < 2; ++kk)
#pragma unroll
      for (int db = 0; db < 8; ++db) {
        bf16x8 vf = *(const bf16x8*)(Vb + (size_t)(db * 16 + lr) * 2048 + kv0 + kk * 32 + lg * 8);
        od[db] = __builtin_amdgcn_mfma_f32_16x16x32_bf16(pa[kk], vf, od[db], 0, 0, 0);
      }
  }
  int b = bh >> 4, h = bh & 15;
#pragma unroll
  for (int db = 0; db < 8; ++db)
#pragma unroll
    for (int r = 0; r < 4; ++r) {
      int q = wq0 + lg * 4 + r;
      float v = od[db][r] / l_run[r];
      O[(size_t)(b * 2048 + q) * 2048 + h * 128 + db * 16 + lr] = (bf16)v;
    }
}

// ---------------------------------------------------------------------------
extern "C" void kernel_launch(void* const* d_in, const int* in_sizes, int n_in,
                              void* d_out, int out_size, void* d_ws, size_t ws_size,
                              hipStream_t stream) {
  const float* x    = (const float*)d_in[0];
  const float* cosb = (const float*)d_in[1];
  const float* sinb = (const float*)d_in[2];
  const float* Wq   = (const float*)d_in[3];
  const float* Wk   = (const float*)d_in[4];
  const float* Wv   = (const float*)d_in[5];
  const float* Wo   = (const float*)d_in[6];
  float* out  = (float*)d_out;                 // [4096][2048]
  float* kout = out + (size_t)8388608;         // [2,16,2048,128]
  float* vout = out + (size_t)16777216;

  char* ws = (char*)d_ws;
  bf16* xb  = (bf16*)(ws);                              // 16MB
  bf16* WqT = (bf16*)(ws + (size_t)16777216);
  bf16* WkT = (bf16*)(ws + (size_t)25165824);
  bf16* WvT = (bf16*)(ws + (size_t)33554432);
  bf16* WoT = (bf16*)(ws + (size_t)41943040);
  bf16* qb  = (bf16*)(ws + (size_t)50331648);
  bf16* kb  = (bf16*)(ws + (size_t)67108864);
  bf16* vb  = (bf16*)(ws + (size_t)83886080);
  bf16* vt  = (bf16*)(ws + (size_t)100663296);
  bf16* ao  = xb;  // x dead after QKV GEMM; reuse as attn-out [4096][2048] bf16

  k_convert<<<8192, 256, 0, stream>>>(x, xb, 2097152);
  k_transpose_w<<<dim3(64, 64, 4), dim3(32, 8), 0, stream>>>(Wq, Wk, Wv, Wo,
                                                             WqT, WkT, WvT, WoT);
  k_gemm<0><<<dim3(32, 16, 3), 256, 0, stream>>>(xb, WqT, WkT, WvT,
                                                 qb, kb, vb, nullptr);
  k_rope<<<16384, 256, 0, stream>>>(qb, kb, vb, cosb, sinb, kout, vout);
  k_vt<<<dim3(64, 4, 32), dim3(32, 8), 0, stream>>>(vb, vt);
  k_attn<<<dim3(32, 32), 256, 0, stream>>>(qb, kb, vt, ao);
  k_gemm<1><<<dim3(32, 16, 1), 256, 0, stream>>>(ao, WoT, nullptr, nullptr,
                                                 nullptr, nullptr, nullptr, out);
}

// Round 9
// 605.201 us; speedup vs baseline: 1.4109x; 1.4109x over previous
//
#include <hip/hip_runtime.h>

// ---------------------------------------------------------------------------
// TemporalAttention: x@Wq/Wk/Wv -> RoPE -> causal SDPA -> @Wo
// B=2 T=2048 DM=2048 H=16 HD=128.  Outputs: out f32[2,2048,2048],
// k_roped f32[2,16,2048,128], v f32[2,16,2048,128] concatenated in d_out.
// ---------------------------------------------------------------------------

typedef __bf16 bf16;
typedef __attribute__((ext_vector_type(8))) __bf16 bf16x8;
typedef __attribute__((ext_vector_type(4))) __bf16 bf16x4;
typedef __attribute__((ext_vector_type(4))) float f32x4;

__device__ __forceinline__ void gload_lds16(const void* g, void* l) {
  __builtin_amdgcn_global_load_lds((const __attribute__((address_space(1))) void*)g,
                                   (__attribute__((address_space(3))) void*)l, 16, 0, 0);
}

// ---- x f32 -> bf16 (vector4) ----------------------------------------------
__global__ __launch_bounds__(256) void k_convert(const float* __restrict__ in,
                                                 bf16* __restrict__ out, int n4) {
  int i = blockIdx.x * 256 + threadIdx.x;
  if (i >= n4) return;
  float4 v = ((const float4*)in)[i];
  bf16x4 o;
  o.x = (bf16)v.x; o.y = (bf16)v.y; o.z = (bf16)v.z; o.w = (bf16)v.w;
  ((bf16x4*)out)[i] = o;
}

// ---- W [K][N] f32 -> WT [N][K] bf16, 4 matrices via z ----------------------
__global__ __launch_bounds__(256) void k_transpose_w(
    const float* __restrict__ W0, const float* __restrict__ W1,
    const float* __restrict__ W2, const float* __restrict__ W3,
    bf16* __restrict__ T0, bf16* __restrict__ T1,
    bf16* __restrict__ T2, bf16* __restrict__ T3) {
  __shared__ float tile[32][33];
  const float* W; bf16* To;
  switch (blockIdx.z) {
    case 0: W = W0; To = T0; break;
    case 1: W = W1; To = T1; break;
    case 2: W = W2; To = T2; break;
    default: W = W3; To = T3; break;
  }
  int n0 = blockIdx.x * 32, k0 = blockIdx.y * 32;
  int tx = threadIdx.x, ty = threadIdx.y;  // (32,8)
#pragma unroll
  for (int j = 0; j < 4; ++j)
    tile[ty + 8 * j][tx] = W[(size_t)(k0 + ty + 8 * j) * 2048 + n0 + tx];
  __syncthreads();
#pragma unroll
  for (int j = 0; j < 4; ++j)
    To[(size_t)(n0 + ty + 8 * j) * 2048 + k0 + tx] = (bf16)tile[tx][ty + 8 * j];
}

// ---- GEMM C[4096x2048] = A[4096x2048] * Bt^T  (Bt is [N][K] row-major) -----
// 128x128 tile, BK=64, 4 waves each 64x64, mfma_f32_16x16x32_bf16.
// MODE 0: write bf16 into [B,H,T,HD] (z selects Wq/Wk/Wv). MODE 1: f32 row-major.
template <int MODE>
__global__ __launch_bounds__(256) void k_gemm(
    const bf16* __restrict__ A, const bf16* __restrict__ B0,
    const bf16* __restrict__ B1, const bf16* __restrict__ B2,
    bf16* __restrict__ o0, bf16* __restrict__ o1, bf16* __restrict__ o2,
    float* __restrict__ outf) {
  __shared__ __align__(16) bf16 Al[128 * 64];
  __shared__ __align__(16) bf16 Bl[128 * 64];
  const bf16* Bt; bf16* outb = nullptr;
  if (MODE == 0) {
    switch (blockIdx.z) {
      case 0: Bt = B0; outb = o0; break;
      case 1: Bt = B1; outb = o1; break;
      default: Bt = B2; outb = o2; break;
    }
  } else {
    Bt = B0;
  }
  int t = threadIdx.x;
  int wv = t >> 6, lane = t & 63, lr = lane & 15, lg = lane >> 4;
  int wr = wv >> 1, wc = wv & 1;
  int row0 = blockIdx.x * 128, col0 = blockIdx.y * 128;
  f32x4 acc[4][4] = {};
  for (int kt = 0; kt < 32; ++kt) {
    int k0 = kt * 64;
#pragma unroll
    for (int it = 0; it < 4; ++it) {
      int ci = it * 256 + t;            // chunk 0..1023, 16B each
      int r = ci >> 3, c8 = (ci & 7) * 8;
      int base = __builtin_amdgcn_readfirstlane(it * 256 + (t & ~63));
      gload_lds16(A + (size_t)(row0 + r) * 2048 + k0 + c8, Al + (size_t)base * 8);
      gload_lds16(Bt + (size_t)(col0 + r) * 2048 + k0 + c8, Bl + (size_t)base * 8);
    }
    __syncthreads();
#pragma unroll
    for (int kk = 0; kk < 2; ++kk) {
      bf16x8 af[4], bfr[4];
#pragma unroll
      for (int mf = 0; mf < 4; ++mf)
        af[mf] = *(const bf16x8*)(Al + (wr * 64 + mf * 16 + lr) * 64 + kk * 32 + lg * 8);
#pragma unroll
      for (int nf = 0; nf < 4; ++nf)
        bfr[nf] = *(const bf16x8*)(Bl + (wc * 64 + nf * 16 + lr) * 64 + kk * 32 + lg * 8);
#pragma unroll
      for (int mf = 0; mf < 4; ++mf)
#pragma unroll
        for (int nf = 0; nf < 4; ++nf)
          acc[mf][nf] = __builtin_amdgcn_mfma_f32_16x16x32_bf16(af[mf], bfr[nf], acc[mf][nf], 0, 0, 0);
    }
    __syncthreads();
  }
#pragma unroll
  for (int mf = 0; mf < 4; ++mf)
#pragma unroll
    for (int nf = 0; nf < 4; ++nf)
#pragma unroll
      for (int r = 0; r < 4; ++r) {
        int row = row0 + wr * 64 + mf * 16 + lg * 4 + r;  // C row (m), verified layout
        int col = col0 + wc * 64 + nf * 16 + lr;          // C col (n)
        float v = acc[mf][nf][r];
        if (MODE == 0) {
          int b = row >> 11, tt = row & 2047, h = col >> 7, d = col & 127;
          outb[(size_t)((b * 16 + h) * 2048 + tt) * 128 + d] = (bf16)v;
        } else {
          outf[(size_t)row * 2048 + col] = v;
        }
      }
}

// ---- RoPE in-place on q,k (bf16); emit k_roped f32 + v f32 outputs ---------
__global__ __launch_bounds__(256) void k_rope(
    bf16* __restrict__ q, bf16* __restrict__ k, const bf16* __restrict__ v,
    const float* __restrict__ cosb, const float* __restrict__ sinb,
    float* __restrict__ kout, float* __restrict__ vout) {
  int tid = blockIdx.x * 256 + threadIdx.x;
  int d = tid & 63;
  int row = tid >> 6;              // (b*16+h)*2048 + t, 0..65535
  int t = row & 2047;
  size_t base = (size_t)row * 128;
  float c1 = cosb[t * 128 + d], c2 = cosb[t * 128 + 64 + d];
  float s1 = sinb[t * 128 + d], s2 = sinb[t * 128 + 64 + d];
  float qlo = (float)q[base + d], qhi = (float)q[base + 64 + d];
  float klo = (float)k[base + d], khi = (float)k[base + 64 + d];
  float ql = qlo * c1 - qhi * s1, qh = qhi * c2 + qlo * s2;
  float kl = klo * c1 - khi * s1, kh = khi * c2 + klo * s2;
  q[base + d] = (bf16)ql; q[base + 64 + d] = (bf16)qh;
  k[base + d] = (bf16)kl; k[base + 64 + d] = (bf16)kh;
  kout[base + d] = kl; kout[base + 64 + d] = kh;
  vout[base + d] = (float)v[base + d];
  vout[base + 64 + d] = (float)v[base + 64 + d];
}

// ---- V [bh][T][HD] -> VT [bh][HD][T] bf16 ----------------------------------
__global__ __launch_bounds__(256) void k_vt(const bf16* __restrict__ v,
                                            bf16* __restrict__ vt) {
  __shared__ bf16 tile[32][33];
  int bh = blockIdx.z;
  int t0 = blockIdx.x * 32, d0 = blockIdx.y * 32;
  int tx = threadIdx.x, ty = threadIdx.y;  // (32,8)
  const bf16* vb = v + (size_t)bh * 2048 * 128;
  bf16* vtb = vt + (size_t)bh * 128 * 2048;
#pragma unroll
  for (int j = 0; j < 4; ++j)
    tile[ty + 8 * j][tx] = vb[(size_t)(t0 + ty + 8 * j) * 128 + d0 + tx];
  __syncthreads();
#pragma unroll
  for (int j = 0; j < 4; ++j)
    vtb[(size_t)(d0 + ty + 8 * j) * 2048 + t0 + tx] = tile[tx][ty + 8 * j];
}

// ---- causal flash attention, swapped-QK^T in-register softmax --------------
// grid (16 qblocks reversed, 32 bh); 4 waves x 32 q-rows each (QBLK=128).
// KV tile = 64.  S^T = mfma(A=K, B=Q): same kf/qf fragments, swapped call.
// Output layout: lane holds S[q=lr][kv = kv0 + c*16 + lg*4 + r] -> softmax is
// per-lane over 16 regs + shfl_xor(16,32).  P -> PV A-fragment via 16 shfl +
// 8 selects (all-lanes, no divergent shuffles).  NO LDS, NO manual waitcnt,
// NO sched_barrier anywhere in the loop (R3/R6's fence construct miscompiled).
// od is q=lg*4+r indexed; cr/l_run (q=lr) bridged by 4 shfl broadcasts.
__global__ __launch_bounds__(256, 2) void k_attn(
    const bf16* __restrict__ Q, const bf16* __restrict__ Kr,
    const bf16* __restrict__ Vt, bf16* __restrict__ O) {
  int t = threadIdx.x, wv = t >> 6, lane = t & 63, lr = lane & 15, lg = lane >> 4;
  int qb = (int)gridDim.x - 1 - (int)blockIdx.x;    // heavy blocks first
  int bh = blockIdx.y;
  int qbase = qb * 128;
  const bf16* Qb = Q + (size_t)bh * 2048 * 128;
  const bf16* Kb = Kr + (size_t)bh * 2048 * 128;
  const bf16* Vb = Vt + (size_t)bh * 128 * 2048;
  int wq[2] = {qbase + wv * 16, qbase + 64 + wv * 16};
  bf16x8 qf[2][4];
#pragma unroll
  for (int mf = 0; mf < 2; ++mf)
#pragma unroll
    for (int df = 0; df < 4; ++df)
      qf[mf][df] = *(const bf16x8*)(Qb + (size_t)(wq[mf] + lr) * 128 + df * 32 + lg * 8);
  f32x4 od[2][8] = {};
  float m_run[2] = {-1e30f, -1e30f}, l_run[2] = {0.f, 0.f};
  const float scale = 0.08838834764831845f;
  int nkt = 2 * qb + 2;
  int s0l = lr + 32 * (lg & 1), s1l = lr + 32 * (lg & 1) + 16;  // shuffle srcs
  bool hi = (lg >> 1) != 0;                                      // c_hi select
  for (int kt = 0; kt < nkt; ++kt) {
    int kv0 = kt * 64;
    // ---- S^T = mfma(K, Q): lane gets S[q=lr][kv = kv0 + c*16 + lg*4 + r] --
    f32x4 s[2][4] = {};
#pragma unroll
    for (int c = 0; c < 4; ++c) {
      bf16x8 kf[4];
#pragma unroll
      for (int df = 0; df < 4; ++df)
        kf[df] = *(const bf16x8*)(Kb + (size_t)(kv0 + c * 16 + lr) * 128 + df * 32 + lg * 8);
#pragma unroll
      for (int mf = 0; mf < 2; ++mf)
#pragma unroll
        for (int df = 0; df < 4; ++df)
          s[mf][c] = __builtin_amdgcn_mfma_f32_16x16x32_bf16(kf[df], qf[mf][df], s[mf][c], 0, 0, 0);
    }
    // ---- prefetch V^T tile into regs (hides under softmax VALU) ----------
    bf16x8 vf[2][8];
#pragma unroll
    for (int kk = 0; kk < 2; ++kk)
#pragma unroll
      for (int db = 0; db < 8; ++db)
        vf[kk][db] = *(const bf16x8*)(Vb + (size_t)(db * 16 + lr) * 2048 + kv0 + kk * 32 + lg * 8);
    bool act0 = (kv0 <= wq[0] + 15);   // wave-uniform; mf1 always active
#pragma unroll
    for (int mf = 0; mf < 2; ++mf) {
      if (mf == 0 && !act0) continue;
      int q = wq[mf] + lr;
      // ---- mask + scale (per-lane row q) ----
      float p[4][4];
#pragma unroll
      for (int c = 0; c < 4; ++c)
#pragma unroll
        for (int r = 0; r < 4; ++r) {
          float v = s[mf][c][r] * scale;
          p[c][r] = (kv0 + c * 16 + lg * 4 + r > q) ? -1e30f : v;
        }
      // ---- online softmax: local 16 + shfl_xor(16,32) ----
      float mx = -1e30f;
#pragma unroll
      for (int c = 0; c < 4; ++c)
#pragma unroll
        for (int r = 0; r < 4; ++r) mx = fmaxf(mx, p[c][r]);
      mx = fmaxf(mx, __shfl_xor(mx, 16));
      mx = fmaxf(mx, __shfl_xor(mx, 32));
      float mnew = fmaxf(m_run[mf], mx);
      float cr = __expf(m_run[mf] - mnew);
      float rs = 0.f;
#pragma unroll
      for (int c = 0; c < 4; ++c)
#pragma unroll
        for (int r = 0; r < 4; ++r) {
          p[c][r] = __expf(p[c][r] - mnew);
          rs += p[c][r];
        }
      rs += __shfl_xor(rs, 16);
      rs += __shfl_xor(rs, 32);
      l_run[mf] = l_run[mf] * cr + rs;
      m_run[mf] = mnew;
      // ---- rescale od (q index = lg*4+r; cr is lg-uniform per lr) ----
      float corr[4];
#pragma unroll
      for (int r = 0; r < 4; ++r)
        corr[r] = __shfl(cr, (lane & 48) | (lg * 4 + r));
#pragma unroll
      for (int db = 0; db < 8; ++db)
#pragma unroll
        for (int r = 0; r < 4; ++r) od[mf][db][r] *= corr[r];
      // ---- pack P to bf16 pairs: pk[c][h] = {p[c][2h], p[c][2h+1]} ----
      unsigned pk[4][2];
#pragma unroll
      for (int c = 0; c < 4; ++c)
#pragma unroll
        for (int h = 0; h < 2; ++h) {
          bf16 b0 = (bf16)p[c][2 * h], b1 = (bf16)p[c][2 * h + 1];
          unsigned u0 = *(const unsigned short*)&b0;
          unsigned u1 = *(const unsigned short*)&b1;
          pk[c][h] = (u1 << 16) | u0;
        }
      // ---- P -> A-frag: dest lane needs P[q=lr][kk*32+lg*8+j] ----
#pragma unroll
      for (int kk = 0; kk < 2; ++kk) {
        unsigned a0 = __shfl(pk[2 * kk][0], s0l);
        unsigned a1 = __shfl(pk[2 * kk][1], s0l);
        unsigned a2 = __shfl(pk[2 * kk][0], s1l);
        unsigned a3 = __shfl(pk[2 * kk][1], s1l);
        unsigned b0 = __shfl(pk[2 * kk + 1][0], s0l);
        unsigned b1 = __shfl(pk[2 * kk + 1][1], s0l);
        unsigned b2 = __shfl(pk[2 * kk + 1][0], s1l);
        unsigned b3 = __shfl(pk[2 * kk + 1][1], s1l);
        union { unsigned u[4]; bf16x8 v; } pw;
        pw.u[0] = hi ? b0 : a0;
        pw.u[1] = hi ? b1 : a1;
        pw.u[2] = hi ? b2 : a2;
        pw.u[3] = hi ? b3 : a3;
#pragma unroll
        for (int db = 0; db < 8; ++db)
          od[mf][db] = __builtin_amdgcn_mfma_f32_16x16x32_bf16(pw.v, vf[kk][db], od[mf][db], 0, 0, 0);
      }
    }
  }
  int b = bh >> 4, h = bh & 15;
#pragma unroll
  for (int mf = 0; mf < 2; ++mf) {
    float ld[4];
#pragma unroll
    for (int r = 0; r < 4; ++r)
      ld[r] = __shfl(l_run[mf], (lane & 48) | (lg * 4 + r));
#pragma unroll
    for (int db = 0; db < 8; ++db)
#pragma unroll
      for (int r = 0; r < 4; ++r) {
        int q = wq[mf] + lg * 4 + r;
        float v = od[mf][db][r] / ld[r];
        O[(size_t)(b * 2048 + q) * 2048 + h * 128 + db * 16 + lr] = (bf16)v;
      }
  }
}

// ---------------------------------------------------------------------------
extern "C" void kernel_launch(void* const* d_in, const int* in_sizes, int n_in,
                              void* d_out, int out_size, void* d_ws, size_t ws_size,
                              hipStream_t stream) {
  const float* x    = (const float*)d_in[0];
  const float* cosb = (const float*)d_in[1];
  const float* sinb = (const float*)d_in[2];
  const float* Wq   = (const float*)d_in[3];
  const float* Wk   = (const float*)d_in[4];
  const float* Wv   = (const float*)d_in[5];
  const float* Wo   = (const float*)d_in[6];
  float* out  = (float*)d_out;                 // [4096][2048]
  float* kout = out + (size_t)8388608;         // [2,16,2048,128]
  float* vout = out + (size_t)16777216;

  char* ws = (char*)d_ws;
  bf16* xb  = (bf16*)(ws);                              // 16MB
  bf16* WqT = (bf16*)(ws + (size_t)16777216);
  bf16* WkT = (bf16*)(ws + (size_t)25165824);
  bf16* WvT = (bf16*)(ws + (size_t)33554432);
  bf16* WoT = (bf16*)(ws + (size_t)41943040);
  bf16* qb  = (bf16*)(ws + (size_t)50331648);
  bf16* kb  = (bf16*)(ws + (size_t)67108864);
  bf16* vb  = (bf16*)(ws + (size_t)83886080);
  bf16* vt  = (bf16*)(ws + (size_t)100663296);
  bf16* ao  = xb;  // x dead after QKV GEMM; reuse as attn-out [4096][2048] bf16

  k_convert<<<8192, 256, 0, stream>>>(x, xb, 2097152);
  k_transpose_w<<<dim3(64, 64, 4), dim3(32, 8), 0, stream>>>(Wq, Wk, Wv, Wo,
                                                             WqT, WkT, WvT, WoT);
  k_gemm<0><<<dim3(32, 16, 3), 256, 0, stream>>>(xb, WqT, WkT, WvT,
                                                 qb, kb, vb, nullptr);
  k_rope<<<16384, 256, 0, stream>>>(qb, kb, vb, cosb, sinb, kout, vout);
  k_vt<<<dim3(64, 4, 32), dim3(32, 8), 0, stream>>>(vb, vt);
  k_attn<<<dim3(16, 32), 256, 0, stream>>>(qb, kb, vt, ao);
  k_gemm<1><<<dim3(32, 16, 1), 256, 0, stream>>>(ao, WoT, nullptr, nullptr,
                                                 nullptr, nullptr, nullptr, out);
}